// Round 1
// baseline (253.824 us; speedup 1.0000x reference)
//
#include <hip/hip_runtime.h>
#include <hip/hip_bf16.h>

typedef _Float16 f16;
typedef _Float16 f16x8 __attribute__((ext_vector_type(8)));
typedef _Float16 f16x4 __attribute__((ext_vector_type(4)));
typedef float f32x4 __attribute__((ext_vector_type(4)));

#define LDS_LOAD16(gptr, lptr)                                                             \
  __builtin_amdgcn_global_load_lds(                                                        \
      (const __attribute__((address_space(1))) unsigned int*)(gptr),                       \
      (__attribute__((address_space(3))) unsigned int*)(lptr), 16, 0, 0)

// ---------------------------------------------------------------------------
// fp32 -> fp16 conversion, 8 elems/thread, vectorized
// ---------------------------------------------------------------------------
__global__ __launch_bounds__(256) void conv_f32_to_f16(const float* __restrict__ src,
                                                       f16* __restrict__ dst, int n8) {
  int i = blockIdx.x * 256 + threadIdx.x;
  if (i >= n8) return;
  const float4* s4 = (const float4*)src;
  float4 a = s4[2 * i];
  float4 b = s4[2 * i + 1];
  f16x8 o = {(f16)a.x, (f16)a.y, (f16)a.z, (f16)a.w,
             (f16)b.x, (f16)b.y, (f16)b.z, (f16)b.w};
  *(f16x8*)(dst + (size_t)i * 8) = o;
}

// ---------------------------------------------------------------------------
// GEMM: C[m][n] = sum_k A[m][k] * Bw[n][k] + bias[n]
// A: MxK row-major f16, Bw: NxK row-major f16.  M=4096, N=1024, K=1024.
// OUTMODE 0/1: write f16 to [B=2][H=16][L=2048][HD=64]   (Q / K layout)
// OUTMODE 2:   write f16 to [B=2][H=16][HD=64][L=2048]   (V transposed)
// OUTMODE 3:   write f32 to [M][N] (final output)
// ---------------------------------------------------------------------------
template <int OUTMODE>
__global__ __launch_bounds__(256) void gemm_bt(const f16* __restrict__ A,
                                               const f16* __restrict__ Bw,
                                               const float* __restrict__ bias,
                                               void* __restrict__ outp) {
  constexpr int N = 1024, K = 1024;
  constexpr int BM = 128, BK = 32;
  __shared__ f16 aT[BM * BK];
  __shared__ f16 bT[BM * BK];
  const int tid = threadIdx.x;
  const int wid = tid >> 6, lane = tid & 63;
  const int mb = blockIdx.y * BM, nb = blockIdx.x * BM;
  const int wr = wid >> 1, wc = wid & 1;
  const int lr = lane & 15, lk8 = (lane >> 4) * 8;

  f32x4 acc[4][4] = {};

  const int ci = wid * 64 + lane;          // chunk index, pass 0
  const int r0 = ci >> 2, s0 = ci & 3;     // row / 8-elem segment (pass 0)
  const int ci1 = 256 + ci;
  const int r1 = ci1 >> 2, s1 = ci1 & 3;   // pass 1

  for (int kt = 0; kt < K / BK; ++kt) {
    __syncthreads();
    const int kb = kt * BK;
    // stage A and B tiles: 128x32 f16 = 8 KB each, 512 chunks of 16B
    LDS_LOAD16(A + (size_t)(mb + r0) * K + kb + s0 * 8, (char*)aT + (wid * 64) * 16);
    LDS_LOAD16(Bw + (size_t)(nb + r0) * K + kb + s0 * 8, (char*)bT + (wid * 64) * 16);
    LDS_LOAD16(A + (size_t)(mb + r1) * K + kb + s1 * 8, (char*)aT + (256 + wid * 64) * 16);
    LDS_LOAD16(Bw + (size_t)(nb + r1) * K + kb + s1 * 8, (char*)bT + (256 + wid * 64) * 16);
    __syncthreads();

    f16x8 af[4], bf[4];
#pragma unroll
    for (int i = 0; i < 4; ++i) af[i] = *(const f16x8*)&aT[(wr * 64 + i * 16 + lr) * BK + lk8];
#pragma unroll
    for (int j = 0; j < 4; ++j) bf[j] = *(const f16x8*)&bT[(wc * 64 + j * 16 + lr) * BK + lk8];
#pragma unroll
    for (int i = 0; i < 4; ++i)
#pragma unroll
      for (int j = 0; j < 4; ++j)
        acc[i][j] = __builtin_amdgcn_mfma_f32_16x16x32_f16(af[i], bf[j], acc[i][j], 0, 0, 0);
  }

  // epilogue.  C layout: col = lane&15, row = (lane>>4)*4 + reg
#pragma unroll
  for (int i = 0; i < 4; ++i) {
#pragma unroll
    for (int j = 0; j < 4; ++j) {
      const int row = mb + wr * 64 + i * 16 + (lane >> 4) * 4;
      const int col = nb + wc * 64 + j * 16 + lr;
      const float bv = bias[col];
      if constexpr (OUTMODE == 3) {
        float* o = (float*)outp;
#pragma unroll
        for (int r = 0; r < 4; ++r) o[(size_t)(row + r) * N + col] = acc[i][j][r] + bv;
      } else if constexpr (OUTMODE == 2) {
        // V^T: [b][h][d][l], rows (=l) are contiguous -> 8B vector store
        f16* o = (f16*)outp;
        const int bb = row >> 11, l = row & 2047;
        const int hh = col >> 6, dd = col & 63;
        f16x4 v4;
#pragma unroll
        for (int r = 0; r < 4; ++r) v4[r] = (f16)(acc[i][j][r] + bv);
        *(f16x4*)((f16*)o + ((((size_t)bb * 16 + hh) * 64 + dd) * 2048 + l)) = v4;
      } else {
        // Q/K: [b][h][l][d]
        f16* o = (f16*)outp;
        const int hh = col >> 6, dd = col & 63;
#pragma unroll
        for (int r = 0; r < 4; ++r) {
          const int m2 = row + r;
          const int bb = m2 >> 11, l = m2 & 2047;
          o[((((size_t)bb * 16 + hh) * 2048 + l) * 64) + dd] = (f16)(acc[i][j][r] + bv);
        }
      }
    }
  }
}

// ---------------------------------------------------------------------------
// Flash attention: 1 WG = one (b,h) x 64 Q rows; 4 waves x 16 rows each.
// KV tiles of 64, K in LDS [kv][d], V^T in LDS [d][kv], online softmax.
// Writes f16 attention output in [B][L][H][HD] (= [4096][1024]) layout.
// ---------------------------------------------------------------------------
__global__ __launch_bounds__(256) void attn64(const f16* __restrict__ Qh,
                                              const f16* __restrict__ Kh,
                                              const f16* __restrict__ Vt,
                                              const int* __restrict__ mask,
                                              f16* __restrict__ Oa) {
  constexpr int L = 2048, HD = 64, H = 16;
  __shared__ f16 kT[64 * 64];
  __shared__ f16 vT[64 * 64];
  __shared__ f16 pT[4][16 * 64];

  const int tid = threadIdx.x, wid = tid >> 6, lane = tid & 63;
  const int bh = blockIdx.y, b = bh >> 4, h = bh & 15;
  const int lr = lane & 15, lk8 = (lane >> 4) * 8;

  const f16* Qb = Qh + (size_t)bh * L * HD;
  const f16* Kb = Kh + (size_t)bh * L * HD;
  const f16* Vb = Vt + (size_t)bh * HD * L;
  const int* mrow = mask + b * L;

  const int qr = blockIdx.x * 64 + wid * 16;
  const f16x8 qf0 = *(const f16x8*)&Qb[(size_t)(qr + lr) * HD + lk8];
  const f16x8 qf1 = *(const f16x8*)&Qb[(size_t)(qr + lr) * HD + 32 + lk8];

  f32x4 oacc[4] = {};
  float mrun[4], lsum[4];
#pragma unroll
  for (int r = 0; r < 4; ++r) { mrun[r] = -INFINITY; lsum[r] = 0.f; }

  const int ci = wid * 64 + lane;
  const int kr0 = ci >> 3, ks0 = ci & 7;
  const int kr1 = (256 + ci) >> 3, ks1 = (256 + ci) & 7;

  for (int kt = 0; kt < L / 64; ++kt) {
    __syncthreads();
    // stage K tile [64][64] and V^T tile [64][64] (8 KB each)
    LDS_LOAD16(Kb + (size_t)(kt * 64 + kr0) * HD + ks0 * 8, (char*)kT + (wid * 64) * 16);
    LDS_LOAD16(Vb + (size_t)kr0 * L + kt * 64 + ks0 * 8, (char*)vT + (wid * 64) * 16);
    LDS_LOAD16(Kb + (size_t)(kt * 64 + kr1) * HD + ks1 * 8, (char*)kT + (256 + wid * 64) * 16);
    LDS_LOAD16(Vb + (size_t)kr1 * L + kt * 64 + ks1 * 8, (char*)vT + (256 + wid * 64) * 16);
    __syncthreads();

    // S = Q K^T  (16 x 64)
    f32x4 s[4];
#pragma unroll
    for (int nf = 0; nf < 4; ++nf) {
      f16x8 kf0 = *(const f16x8*)&kT[(nf * 16 + lr) * 64 + lk8];
      f16x8 kf1 = *(const f16x8*)&kT[(nf * 16 + lr) * 64 + 32 + lk8];
      f32x4 z = {};
      z = __builtin_amdgcn_mfma_f32_16x16x32_f16(qf0, kf0, z, 0, 0, 0);
      z = __builtin_amdgcn_mfma_f32_16x16x32_f16(qf1, kf1, z, 0, 0, 0);
      s[nf] = z;
    }

    // scale + mask (reference: scores/sqrt(64), then where(mask==0, 1e-9))
    float sv[4][4];
#pragma unroll
    for (int nf = 0; nf < 4; ++nf) {
      const int mv = mrow[kt * 64 + nf * 16 + lr];
#pragma unroll
      for (int r = 0; r < 4; ++r) {
        float x = s[nf][r] * 0.125f;
        sv[nf][r] = (mv == 0) ? 1e-9f : x;
      }
    }

    // online softmax: rows live across the 16-lane group (col = lane&15)
    float mnew[4], corr[4], psum[4];
#pragma unroll
    for (int r = 0; r < 4; ++r) {
      float t = fmaxf(fmaxf(sv[0][r], sv[1][r]), fmaxf(sv[2][r], sv[3][r]));
      t = fmaxf(t, __shfl_xor(t, 1));
      t = fmaxf(t, __shfl_xor(t, 2));
      t = fmaxf(t, __shfl_xor(t, 4));
      t = fmaxf(t, __shfl_xor(t, 8));
      mnew[r] = fmaxf(mrun[r], t);
      corr[r] = __expf(mrun[r] - mnew[r]);
      psum[r] = 0.f;
    }
#pragma unroll
    for (int nf = 0; nf < 4; ++nf)
#pragma unroll
      for (int r = 0; r < 4; ++r) {
        float p = __expf(sv[nf][r] - mnew[r]);
        psum[r] += p;
        pT[wid][((lane >> 4) * 4 + r) * 64 + nf * 16 + lr] = (f16)p;
      }
#pragma unroll
    for (int r = 0; r < 4; ++r) {
      psum[r] += __shfl_xor(psum[r], 1);
      psum[r] += __shfl_xor(psum[r], 2);
      psum[r] += __shfl_xor(psum[r], 4);
      psum[r] += __shfl_xor(psum[r], 8);
      lsum[r] = lsum[r] * corr[r] + psum[r];
      mrun[r] = mnew[r];
    }
#pragma unroll
    for (int df = 0; df < 4; ++df)
#pragma unroll
      for (int r = 0; r < 4; ++r) oacc[df][r] *= corr[r];

    // O += P (16x64) x V (64x64); P from per-wave LDS, V^T rows are d
#pragma unroll
    for (int kh = 0; kh < 2; ++kh) {
      f16x8 pf = *(const f16x8*)&pT[wid][lr * 64 + kh * 32 + lk8];
#pragma unroll
      for (int df = 0; df < 4; ++df) {
        f16x8 vf = *(const f16x8*)&vT[(df * 16 + lr) * 64 + kh * 32 + lk8];
        oacc[df] = __builtin_amdgcn_mfma_f32_16x16x32_f16(pf, vf, oacc[df], 0, 0, 0);
      }
    }
  }

  // epilogue: normalize and write [b][l][h][d]
#pragma unroll
  for (int df = 0; df < 4; ++df)
#pragma unroll
    for (int r = 0; r < 4; ++r) {
      const int l = qr + (lane >> 4) * 4 + r;
      Oa[(((size_t)b * L + l) * H + h) * HD + df * 16 + lr] = (f16)(oacc[df][r] / lsum[r]);
    }
}

// ---------------------------------------------------------------------------
extern "C" void kernel_launch(void* const* d_in, const int* in_sizes, int n_in,
                              void* d_out, int out_size, void* d_ws, size_t ws_size,
                              hipStream_t stream) {
  const float* x  = (const float*)d_in[0];
  const int* mask = (const int*)d_in[1];
  const float* Wq = (const float*)d_in[2];
  const float* bq = (const float*)d_in[3];
  const float* Wk = (const float*)d_in[4];
  const float* bk = (const float*)d_in[5];
  const float* Wv = (const float*)d_in[6];
  const float* bv = (const float*)d_in[7];
  const float* Wo = (const float*)d_in[8];
  const float* bo = (const float*)d_in[9];
  float* out = (float*)d_out;

  char* ws = (char*)d_ws;
  const size_t MB = 1u << 20;
  f16* xh  = (f16*)(ws);             // 4096x1024  (8 MB)
  f16* wqh = (f16*)(ws + 8 * MB);    // 1024x1024  (2 MB)
  f16* wkh = (f16*)(ws + 10 * MB);
  f16* wvh = (f16*)(ws + 12 * MB);
  f16* woh = (f16*)(ws + 14 * MB);
  f16* qh  = (f16*)(ws + 16 * MB);   // [2][16][2048][64] (8 MB)
  f16* kh  = (f16*)(ws + 24 * MB);   // [2][16][2048][64]
  f16* vth = (f16*)(ws + 32 * MB);   // [2][16][64][2048]
  f16* oah = (f16*)(ws + 40 * MB);   // [2][2048][16][64] = [4096][1024]

  // fp32 -> fp16
  conv_f32_to_f16<<<2048, 256, 0, stream>>>(x, xh, 524288);
  conv_f32_to_f16<<<512, 256, 0, stream>>>(Wq, wqh, 131072);
  conv_f32_to_f16<<<512, 256, 0, stream>>>(Wk, wkh, 131072);
  conv_f32_to_f16<<<512, 256, 0, stream>>>(Wv, wvh, 131072);
  conv_f32_to_f16<<<512, 256, 0, stream>>>(Wo, woh, 131072);

  // QKV projections (scattered into head layouts)
  dim3 gg(1024 / 128, 4096 / 128);
  gemm_bt<0><<<gg, 256, 0, stream>>>(xh, wqh, bq, qh);
  gemm_bt<1><<<gg, 256, 0, stream>>>(xh, wkh, bk, kh);
  gemm_bt<2><<<gg, 256, 0, stream>>>(xh, wvh, bv, vth);

  // attention
  attn64<<<dim3(2048 / 64, 32), 256, 0, stream>>>(qh, kh, vth, mask, oah);

  // output projection -> fp32 d_out
  gemm_bt<3><<<gg, 256, 0, stream>>>(oah, woh, bo, out);
}

// Round 2
// 130.129 us; speedup vs baseline: 1.9505x; 1.9505x over previous
//
#include <hip/hip_runtime.h>
#include <hip/hip_bf16.h>

typedef _Float16 f16;
typedef _Float16 f16x8 __attribute__((ext_vector_type(8)));
typedef _Float16 f16x4 __attribute__((ext_vector_type(4)));
typedef float f32x4 __attribute__((ext_vector_type(4)));

#define LDS_LOAD16(gptr, lptr)                                                             \
  __builtin_amdgcn_global_load_lds(                                                        \
      (const __attribute__((address_space(1))) unsigned int*)(gptr),                       \
      (__attribute__((address_space(3))) unsigned int*)(lptr), 16, 0, 0)

// 0.125 (1/sqrt(HD)) * log2(e): folded into Q so QK^T yields log2e-scaled scores
#define ALPHA 0.18033688f

// ---------------------------------------------------------------------------
// fused fp32 -> fp16 conversion for x + 4 weight matrices
// ---------------------------------------------------------------------------
__global__ __launch_bounds__(256) void conv_all(const float* __restrict__ x,
                                                const float* __restrict__ Wq,
                                                const float* __restrict__ Wk,
                                                const float* __restrict__ Wv,
                                                const float* __restrict__ Wo,
                                                f16* __restrict__ xh, f16* __restrict__ wqh,
                                                f16* __restrict__ wkh, f16* __restrict__ wvh,
                                                f16* __restrict__ woh) {
  int i = blockIdx.x * 256 + threadIdx.x;  // 0 .. 1048575 (x: 524288, each W: 131072)
  const float* src;
  f16* dst;
  int off;
  if (i < 524288) {
    src = x; dst = xh; off = i;
  } else {
    int j = i - 524288;
    int w = j >> 17;
    off = j & 131071;
    src = (w == 0) ? Wq : (w == 1) ? Wk : (w == 2) ? Wv : Wo;
    dst = (w == 0) ? wqh : (w == 1) ? wkh : (w == 2) ? wvh : woh;
  }
  const float4* s4 = (const float4*)src;
  float4 a = s4[2 * off];
  float4 b = s4[2 * off + 1];
  f16x8 o = {(f16)a.x, (f16)a.y, (f16)a.z, (f16)a.w,
             (f16)b.x, (f16)b.y, (f16)b.z, (f16)b.w};
  *(f16x8*)(dst + (size_t)off * 8) = o;
}

// ---------------------------------------------------------------------------
// Fused QKV projection: z=0 -> Q (scaled by ALPHA), z=1 -> K, z=2 -> V^T.
// C[m][n] = (sum_k A[m][k]*W[n][k] + bias[n]) [* ALPHA]
// 128x128 tile, 4 waves, 16x16x32 MFMA.  3*256=768 blocks -> 3 blocks/CU.
// ---------------------------------------------------------------------------
__global__ __launch_bounds__(256) void gemm_qkv(const f16* __restrict__ A,
                                                const f16* __restrict__ W0,
                                                const f16* __restrict__ W1,
                                                const f16* __restrict__ W2,
                                                const float* __restrict__ b0,
                                                const float* __restrict__ b1,
                                                const float* __restrict__ b2,
                                                f16* __restrict__ qo, f16* __restrict__ ko,
                                                f16* __restrict__ vo) {
  constexpr int K = 1024, BM = 128, BK = 32;
  __shared__ f16 aT[BM * BK];
  __shared__ f16 bT[BM * BK];
  const int z = blockIdx.z;
  const f16* Bw = (z == 0) ? W0 : (z == 1) ? W1 : W2;
  const float* bias = (z == 0) ? b0 : (z == 1) ? b1 : b2;
  const int tid = threadIdx.x, wid = tid >> 6, lane = tid & 63;
  const int mb = blockIdx.y * BM, nb = blockIdx.x * BM;
  const int wr = wid >> 1, wc = wid & 1;
  const int lr = lane & 15, hi = lane >> 4;

  f32x4 acc[4][4] = {};

  const int r0 = tid >> 2, s0 = tid & 3;
  const int ci1 = 256 + tid, r1 = ci1 >> 2, s1 = ci1 & 3;

  for (int kt = 0; kt < K / BK; ++kt) {
    __syncthreads();
    const int kb = kt * BK;
    LDS_LOAD16(A + (size_t)(mb + r0) * K + kb + s0 * 8, (char*)aT + wid * 1024);
    LDS_LOAD16(Bw + (size_t)(nb + r0) * K + kb + s0 * 8, (char*)bT + wid * 1024);
    LDS_LOAD16(A + (size_t)(mb + r1) * K + kb + s1 * 8, (char*)aT + 4096 + wid * 1024);
    LDS_LOAD16(Bw + (size_t)(nb + r1) * K + kb + s1 * 8, (char*)bT + 4096 + wid * 1024);
    __syncthreads();

    f16x8 af[4], bf[4];
#pragma unroll
    for (int i = 0; i < 4; ++i) af[i] = *(const f16x8*)&aT[(wr * 64 + i * 16 + lr) * BK + hi * 8];
#pragma unroll
    for (int j = 0; j < 4; ++j) bf[j] = *(const f16x8*)&bT[(wc * 64 + j * 16 + lr) * BK + hi * 8];
    __builtin_amdgcn_s_setprio(1);
#pragma unroll
    for (int i = 0; i < 4; ++i)
#pragma unroll
      for (int j = 0; j < 4; ++j)
        acc[i][j] = __builtin_amdgcn_mfma_f32_16x16x32_f16(af[i], bf[j], acc[i][j], 0, 0, 0);
    __builtin_amdgcn_s_setprio(0);
  }

  const float scale = (z == 0) ? ALPHA : 1.0f;
#pragma unroll
  for (int i = 0; i < 4; ++i) {
#pragma unroll
    for (int j = 0; j < 4; ++j) {
      const int row = mb + wr * 64 + i * 16 + hi * 4;
      const int col = nb + wc * 64 + j * 16 + lr;
      const float bv = bias[col];
      const int hh = col >> 6, dd = col & 63;
      if (z == 2) {
        // V^T: [b][h][d][l], l contiguous -> 8B vector store
        const int bb = row >> 11, l = row & 2047;
        f16x4 v4;
#pragma unroll
        for (int r = 0; r < 4; ++r) v4[r] = (f16)(acc[i][j][r] + bv);
        *(f16x4*)(vo + ((((size_t)bb * 16 + hh) * 64 + dd) * 2048 + l)) = v4;
      } else {
        f16* o = z ? ko : qo;
#pragma unroll
        for (int r = 0; r < 4; ++r) {
          const int m2 = row + r;
          const int bb = m2 >> 11, l = m2 & 2047;
          o[((((size_t)bb * 16 + hh) * 2048 + l) * 64) + dd] = (f16)((acc[i][j][r] + bv) * scale);
        }
      }
    }
  }
}

// ---------------------------------------------------------------------------
// Output projection: 64x64 tile (1024 blocks -> 4/CU occupancy), f32 out.
// ---------------------------------------------------------------------------
__global__ __launch_bounds__(256) void gemm_out(const f16* __restrict__ A,
                                                const f16* __restrict__ W,
                                                const float* __restrict__ bias,
                                                float* __restrict__ out) {
  constexpr int K = 1024, N = 1024, BK = 32;
  __shared__ f16 aT[64 * BK];
  __shared__ f16 bT[64 * BK];
  const int tid = threadIdx.x, wid = tid >> 6, lane = tid & 63;
  const int lr = lane & 15, hi = lane >> 4;
  const int mb = blockIdx.y * 64, nb = blockIdx.x * 64;
  f32x4 acc[4] = {};
  const int r0 = tid >> 2, s0 = tid & 3;

  for (int kt = 0; kt < K / BK; ++kt) {
    __syncthreads();
    const int kb = kt * BK;
    LDS_LOAD16(A + (size_t)(mb + r0) * K + kb + s0 * 8, (char*)aT + wid * 1024);
    LDS_LOAD16(W + (size_t)(nb + r0) * K + kb + s0 * 8, (char*)bT + wid * 1024);
    __syncthreads();
    f16x8 af = *(const f16x8*)&aT[(wid * 16 + lr) * BK + hi * 8];
    __builtin_amdgcn_s_setprio(1);
#pragma unroll
    for (int j = 0; j < 4; ++j) {
      f16x8 bf = *(const f16x8*)&bT[(j * 16 + lr) * BK + hi * 8];
      acc[j] = __builtin_amdgcn_mfma_f32_16x16x32_f16(af, bf, acc[j], 0, 0, 0);
    }
    __builtin_amdgcn_s_setprio(0);
  }
#pragma unroll
  for (int j = 0; j < 4; ++j) {
    const int col = nb + j * 16 + lr;
    const float bv = bias[col];
#pragma unroll
    for (int r = 0; r < 4; ++r)
      out[(size_t)(mb + wid * 16 + hi * 4 + r) * N + col] = acc[j][r] + bv;
  }
}

// ---------------------------------------------------------------------------
// Flash attention, fixed-offset softmax (no online max).
// Q pre-scaled by 0.125*log2e, so p = exp2(qk - 8); softmax invariant to -8.
// kT/vT/pT all XOR-swizzled (byte ^= (row&7)<<4); kT/vT achieve this with a
// pre-swizzled global_load_lds SOURCE chunk index (LDS stays linear).
// ---------------------------------------------------------------------------
__global__ __launch_bounds__(256) void attn64(const f16* __restrict__ Qh,
                                              const f16* __restrict__ Kh,
                                              const f16* __restrict__ Vt,
                                              const int* __restrict__ mask,
                                              f16* __restrict__ Oa) {
  constexpr int L = 2048, HD = 64, H = 16;
  __shared__ f16 kT[64 * 64];
  __shared__ f16 vT[64 * 64];
  __shared__ f16 pT[4 * 16 * 64];

  const int tid = threadIdx.x, wid = tid >> 6, lane = tid & 63;
  const int bh = blockIdx.y, b = bh >> 4, h = bh & 15;
  const int lr = lane & 15, hi = lane >> 4;
  const int xr = (lr & 7) << 4;  // read-side XOR swizzle (bits 4..6 of byte addr)

  const f16* Qb = Qh + (size_t)bh * L * HD;
  const f16* Kb = Kh + (size_t)bh * L * HD;
  const f16* Vb = Vt + (size_t)bh * HD * L;
  const int* mrow = mask + b * L;

  const int qr = blockIdx.x * 64 + wid * 16;
  const f16x8 qf0 = *(const f16x8*)&Qb[(size_t)(qr + lr) * HD + hi * 8];
  const f16x8 qf1 = *(const f16x8*)&Qb[(size_t)(qr + lr) * HD + 32 + hi * 8];

  f32x4 oacc[4] = {};
  float lsum[4] = {0.f, 0.f, 0.f, 0.f};

  // staging: chunk n -> row n>>3, source chunk (n&7)^(row&7)  (write-side swizzle
  // realized by permuting the per-lane GLOBAL address; LDS dest is linear)
  const int kr0 = tid >> 3, ks0 = (tid & 7) ^ (kr0 & 7);
  const int ci1 = 256 + tid;
  const int kr1 = ci1 >> 3, ks1 = (ci1 & 7) ^ (kr1 & 7);

  char* kTb = (char*)kT;
  char* vTb = (char*)vT;
  char* pTb = (char*)pT + wid * 2048;

  for (int kt = 0; kt < L / 64; ++kt) {
    __syncthreads();
    LDS_LOAD16(Kb + (size_t)(kt * 64 + kr0) * HD + ks0 * 8, kTb + wid * 1024);
    LDS_LOAD16(Vb + (size_t)kr0 * L + kt * 64 + ks0 * 8, vTb + wid * 1024);
    LDS_LOAD16(Kb + (size_t)(kt * 64 + kr1) * HD + ks1 * 8, kTb + 4096 + wid * 1024);
    LDS_LOAD16(Vb + (size_t)kr1 * L + kt * 64 + ks1 * 8, vTb + 4096 + wid * 1024);
    __syncthreads();

    // S = Q K^T (16 x 64), C-init = -8 folds the softmax offset
    f32x4 s[4];
    __builtin_amdgcn_s_setprio(1);
#pragma unroll
    for (int nf = 0; nf < 4; ++nf) {
      const char* krow = kTb + (nf * 16 + lr) * 128;
      f16x8 kf0 = *(const f16x8*)(krow + ((hi * 16) ^ xr));
      f16x8 kf1 = *(const f16x8*)(krow + ((hi * 16) ^ xr ^ 64));
      f32x4 z = {-8.f, -8.f, -8.f, -8.f};
      z = __builtin_amdgcn_mfma_f32_16x16x32_f16(qf0, kf0, z, 0, 0, 0);
      z = __builtin_amdgcn_mfma_f32_16x16x32_f16(qf1, kf1, z, 0, 0, 0);
      s[nf] = z;
    }
    __builtin_amdgcn_s_setprio(0);

    // p = exp2(s); accumulate row-sum partials; write P to swizzled LDS
#pragma unroll
    for (int nf = 0; nf < 4; ++nf) {
      const int mv = mrow[kt * 64 + nf * 16 + lr];
#pragma unroll
      for (int r = 0; r < 4; ++r) {
        float t = mv ? s[nf][r] : (1.44269504e-9f - 8.0f);
        float p = __builtin_amdgcn_exp2f(t);
        lsum[r] += p;
        const int qrow = hi * 4 + r;
        *(f16*)(pTb + qrow * 128 + ((nf * 32 + lr * 2) ^ ((qrow & 7) << 4))) = (f16)p;
      }
    }

    // O += P (16x64) x V (64x64)
    __builtin_amdgcn_s_setprio(1);
#pragma unroll
    for (int kh = 0; kh < 2; ++kh) {
      f16x8 pf = *(const f16x8*)(pTb + lr * 128 + (((4 * kh + hi) * 16) ^ xr));
#pragma unroll
      for (int df = 0; df < 4; ++df) {
        f16x8 vf = *(const f16x8*)(vTb + (df * 16 + lr) * 128 + (((4 * kh + hi) * 16) ^ xr));
        oacc[df] = __builtin_amdgcn_mfma_f32_16x16x32_f16(pf, vf, oacc[df], 0, 0, 0);
      }
    }
    __builtin_amdgcn_s_setprio(0);
  }

  // deferred row-sum reduce across the 16-lane column groups
#pragma unroll
  for (int r = 0; r < 4; ++r) {
    float t = lsum[r];
    t += __shfl_xor(t, 1);
    t += __shfl_xor(t, 2);
    t += __shfl_xor(t, 4);
    t += __shfl_xor(t, 8);
    lsum[r] = 1.0f / t;
  }
#pragma unroll
  for (int df = 0; df < 4; ++df)
#pragma unroll
    for (int r = 0; r < 4; ++r) {
      const int l = qr + hi * 4 + r;
      Oa[(((size_t)b * L + l) * H + h) * HD + df * 16 + lr] = (f16)(oacc[df][r] * lsum[r]);
    }
}

// ---------------------------------------------------------------------------
extern "C" void kernel_launch(void* const* d_in, const int* in_sizes, int n_in,
                              void* d_out, int out_size, void* d_ws, size_t ws_size,
                              hipStream_t stream) {
  const float* x  = (const float*)d_in[0];
  const int* mask = (const int*)d_in[1];
  const float* Wq = (const float*)d_in[2];
  const float* bq = (const float*)d_in[3];
  const float* Wk = (const float*)d_in[4];
  const float* bk = (const float*)d_in[5];
  const float* Wv = (const float*)d_in[6];
  const float* bv = (const float*)d_in[7];
  const float* Wo = (const float*)d_in[8];
  const float* bo = (const float*)d_in[9];
  float* out = (float*)d_out;

  char* ws = (char*)d_ws;
  const size_t MB = 1u << 20;
  f16* xh  = (f16*)(ws);             // 4096x1024  (8 MB)
  f16* wqh = (f16*)(ws + 8 * MB);    // 1024x1024  (2 MB)
  f16* wkh = (f16*)(ws + 10 * MB);
  f16* wvh = (f16*)(ws + 12 * MB);
  f16* woh = (f16*)(ws + 14 * MB);
  f16* qh  = (f16*)(ws + 16 * MB);   // [2][16][2048][64] (8 MB), pre-scaled by ALPHA
  f16* kh  = (f16*)(ws + 24 * MB);   // [2][16][2048][64]
  f16* vth = (f16*)(ws + 32 * MB);   // [2][16][64][2048]
  f16* oah = (f16*)(ws + 40 * MB);   // [2][2048][16][64] = [4096][1024]

  conv_all<<<4096, 256, 0, stream>>>(x, Wq, Wk, Wv, Wo, xh, wqh, wkh, wvh, woh);

  gemm_qkv<<<dim3(8, 32, 3), 256, 0, stream>>>(xh, wqh, wkh, wvh, bq, bk, bv, qh, kh, vth);

  attn64<<<dim3(2048 / 64, 32), 256, 0, stream>>>(qh, kh, vth, mask, oah);

  gemm_out<<<dim3(16, 64), 256, 0, stream>>>(oah, woh, bo, out);
}